// Round 5
// baseline (19678.400 us; speedup 1.0000x reference)
//
#include <hip/hip_runtime.h>
#include <hip/hip_bf16.h>

// TGCN: B=64, T=500, N=21, HID=128.
// One block per batch element (64 x 256 threads), full T-loop in-kernel.
// Round 5 (from round-4 G=4/F=2/RPT=6 structure):
//  1. Only 2 true __syncthreads per step (after P2: cross-wave H1 read in P3;
//     end of step: sax from wave 0). P1->P2, P3->P4, P4->P5 communicate only
//     within a wave (wave g's 64 lanes cover all 128 cols of rows 6g..6g+5),
//     so a wave-local "s_waitcnt lgkmcnt(0)" + compiler fence suffices —
//     removing 3 barrier drains (incl. vmcnt(0)) per step.
//  2. Distance-1 software-pipelined loads (next-c weights + LDS H chunks
//     before current FMAs) — safe now: 1 wave/SIMD => 512-VGPR budget.
// Accumulation order is BIT-IDENTICAL to round 4 (passing): c ascending,
// fma4 x..w, a-then-g chunk per c in P4. Never reorder sums in recurrence.

#define NN 21
#define NROW 24            // padded rows (21,22,23 are zero rows)
#define HID 128
#define TSTEPS 500
#define EDGES 210
#define NTHREADS 256       // 4 waves
#define RPT 6              // rows per thread

// ws layout (float offsets)
#define WS_A     0        // NROW*NN floats (pad rows zeroed on build)
#define WS_VEC   1600     // 9*128
#define WS_LZR1  3200     // 32*256*4
#define WS_LH1   36000    // 32*128*4
#define WS_WE2   52400    // 32*384*4
#define WS_LZR2  101600   // 32*256*4
#define WS_LH2   134400   // 32*128*4

// Wave-local LDS release: all prior ds_writes complete before we proceed.
// HW: lgkmcnt(0) drains the wave's LDS queue. Compiler: "memory" clobber
// stops reordering of LDS accesses across it. No inter-wave sync, no vmcnt
// drain (in-flight global weight prefetches keep flying).
#define WAVE_SYNC() asm volatile("s_waitcnt lgkmcnt(0)" ::: "memory")

__device__ __forceinline__ float fma4(float4 a, float4 b, float acc) {
    acc = fmaf(a.x, b.x, acc);
    acc = fmaf(a.y, b.y, acc);
    acc = fmaf(a.z, b.z, acc);
    acc = fmaf(a.w, b.w, acc);
    return acc;
}

__device__ __forceinline__ float sigmoidf(float v) {
    return 1.0f / (1.0f + expf(-v));
}

// ---- Prologue: build normalized adjacency A (21x21) in fp64, store fp32 ----
__global__ void build_A(const int* __restrict__ ei, const float* __restrict__ ew,
                        float* __restrict__ Aout) {
    __shared__ double deg[NN];
    __shared__ double dinv[NN];
    __shared__ double Asm[NN * NN];
    int t = threadIdx.x;
    for (int k = t; k < NN * NN; k += blockDim.x) Asm[k] = 0.0;
    if (t < NN) deg[t] = 1.0;  // self loop weight 1
    __syncthreads();
    if (t == 0) {
        for (int e = 0; e < EDGES; e++) deg[ei[EDGES + e]] += (double)ew[e];
        for (int i = 0; i < NN; i++) dinv[i] = deg[i] > 0.0 ? 1.0 / sqrt(deg[i]) : 0.0;
        for (int e = 0; e < EDGES; e++) {
            int s = ei[e], d = ei[EDGES + e];
            Asm[d * NN + s] += dinv[s] * (double)ew[e] * dinv[d];
        }
        for (int i = 0; i < NN; i++) Asm[i * NN + i] += dinv[i] * dinv[i];
    }
    __syncthreads();
    for (int k = t; k < NROW * NN; k += blockDim.x)
        Aout[k] = (k < NN * NN) ? (float)Asm[k] : 0.0f;
}

// ---- Prologue: repack bottom halves of (256,128) concat weights ----
__global__ void pack_bot(const float* __restrict__ w0, const float* __restrict__ w1,
                         float4* __restrict__ out, int ngate) {
    int t = blockIdx.x * blockDim.x + threadIdx.x;
    int ncol = ngate * 128;
    int total = 32 * ncol;
    if (t >= total) return;
    int c = t / ncol, col = t - c * ncol;
    const float* src = (col < 128) ? w0 : w1;
    int f = col & 127;
    int k = 4 * c;
    float4 v;
    v.x = src[(128 + k + 0) * 128 + f];
    v.y = src[(128 + k + 1) * 128 + f];
    v.z = src[(128 + k + 2) * 128 + f];
    v.w = src[(128 + k + 3) * 128 + f];
    out[t] = v;
}

// ---- Prologue: Weff2_g = Wg_2 @ lgw_2_top, packed [c][g*128+f], fp64 accum ----
__global__ void make_weff2(const float* __restrict__ Wz2, const float* __restrict__ Wr2,
                           const float* __restrict__ Wh2,
                           const float* __restrict__ lzw2, const float* __restrict__ lrw2,
                           const float* __restrict__ lhw2,
                           float4* __restrict__ out) {
    int t = blockIdx.x * blockDim.x + threadIdx.x;  // [0, 32*384)
    if (t >= 32 * 384) return;
    int c = t / 384, col = t - c * 384;
    int g = col >> 7, f = col & 127;
    const float* W = (g == 0) ? Wz2 : (g == 1) ? Wr2 : Wh2;
    const float* L = (g == 0) ? lzw2 : (g == 1) ? lrw2 : lhw2;
    double a0 = 0, a1 = 0, a2 = 0, a3 = 0;
    for (int m = 0; m < 128; m++) {
        double lm = (double)L[m * 128 + f];
        a0 += (double)W[(4 * c + 0) * 128 + m] * lm;
        a1 += (double)W[(4 * c + 1) * 128 + m] * lm;
        a2 += (double)W[(4 * c + 2) * 128 + m] * lm;
        a3 += (double)W[(4 * c + 3) * 128 + m] * lm;
    }
    out[t] = make_float4((float)a0, (float)a1, (float)a2, (float)a3);
}

// ---- Prologue: layer-1 effective row vectors + all bias consts (fp64) ----
__global__ void make_vecs(const float* __restrict__ Wz1, const float* __restrict__ Wr1,
                          const float* __restrict__ Wh1,
                          const float* __restrict__ bz1, const float* __restrict__ br1,
                          const float* __restrict__ bh1,
                          const float* __restrict__ lzw1, const float* __restrict__ lrw1,
                          const float* __restrict__ lhw1,
                          const float* __restrict__ lzb1, const float* __restrict__ lrb1,
                          const float* __restrict__ lhb1,
                          const float* __restrict__ bz2, const float* __restrict__ br2,
                          const float* __restrict__ bh2,
                          const float* __restrict__ lzw2, const float* __restrict__ lrw2,
                          const float* __restrict__ lhw2,
                          const float* __restrict__ lzb2, const float* __restrict__ lrb2,
                          const float* __restrict__ lhb2,
                          float* __restrict__ out) {
    int t = blockIdx.x * blockDim.x + threadIdx.x;
    if (t >= 9 * 128) return;
    int v = t >> 7, f = t & 127;
    double acc = 0.0;
    if (v < 3) {
        const float* W = (v == 0) ? Wz1 : (v == 1) ? Wr1 : Wh1;   // (1,128)
        const float* L = (v == 0) ? lzw1 : (v == 1) ? lrw1 : lhw1;
        for (int m = 0; m < 128; m++) acc += (double)W[m] * (double)L[m * 128 + f];
    } else if (v < 6) {
        int g = v - 3;
        const float* bb = (g == 0) ? bz1 : (g == 1) ? br1 : bh1;
        const float* L  = (g == 0) ? lzw1 : (g == 1) ? lrw1 : lhw1;
        const float* lb = (g == 0) ? lzb1 : (g == 1) ? lrb1 : lhb1;
        for (int m = 0; m < 128; m++) acc += (double)bb[m] * (double)L[m * 128 + f];
        acc += (double)lb[f];
    } else {
        int g = v - 6;
        const float* bb = (g == 0) ? bz2 : (g == 1) ? br2 : bh2;
        const float* L  = (g == 0) ? lzw2 : (g == 1) ? lrw2 : lhw2;
        const float* lb = (g == 0) ? lzb2 : (g == 1) ? lrb2 : lhb2;
        for (int m = 0; m < 128; m++) acc += (double)bb[m] * (double)L[m * 128 + f];
        acc += (double)lb[f];
    }
    out[t] = (float)acc;
}

// ---- Main: one block per batch element, T=500 steps in-kernel ----
__global__ __launch_bounds__(NTHREADS, 1) void tgcn_main(
    const float* __restrict__ x,       // (64,500,21)
    const float* __restrict__ ws,
    const float* __restrict__ cls_w,   // (128,1)
    const float* __restrict__ cls_b,   // (1,)
    float* __restrict__ out)           // (64,)
{
    const int b  = blockIdx.x;
    const int t  = threadIdx.x;
    const int f0 = t & 63;
    const int f1 = f0 + 64;
    const int g  = __builtin_amdgcn_readfirstlane(t >> 6);  // wave-uniform 0..3
    const int iA = g * RPT;                                 // first owned row
    const int nreal = (iA + RPT <= NN) ? RPT : (NN - iA);   // real rows (wave-uniform)

    __shared__ __align__(16) float sH1[NROW * HID];
    __shared__ __align__(16) float sH2[NROW * HID];
    __shared__ __align__(16) float sHR[NROW * HID];
    __shared__ __align__(16) float sAH[NROW * HID];
    __shared__ float sA[NROW * NN];    // pad rows zero
    __shared__ float sax[2][NROW];
    __shared__ double sred[4][HID];

    const float*  vecs = ws + WS_VEC;
    const float4* Lzr1 = (const float4*)(ws + WS_LZR1);
    const float4* Lh1  = (const float4*)(ws + WS_LH1);
    const float4* We2  = (const float4*)(ws + WS_WE2);
    const float4* Lzr2 = (const float4*)(ws + WS_LZR2);
    const float4* Lh2  = (const float4*)(ws + WS_LH2);

    const float4* H1v = (const float4*)sH1;   // row stride 32 float4
    const float4* H2v = (const float4*)sH2;
    const float4* HRv = (const float4*)sHR;
    const float4* AHv = (const float4*)sAH;

    for (int k = t; k < NROW * HID; k += NTHREADS) { sH1[k] = 0.0f; sH2[k] = 0.0f; }
    for (int k = t; k < NROW * NN; k += NTHREADS) sA[k] = ws[WS_A + k];

    // per-column constants for both owned columns
    const float wz1a = vecs[f0],        wz1b = vecs[f1];
    const float wr1a = vecs[128 + f0],  wr1b = vecs[128 + f1];
    const float wh1a = vecs[256 + f0],  wh1b = vecs[256 + f1];
    const float cz1a = vecs[384 + f0],  cz1b = vecs[384 + f1];
    const float cr1a = vecs[512 + f0],  cr1b = vecs[512 + f1];
    const float ch1a = vecs[640 + f0],  ch1b = vecs[640 + f1];
    const float cz2a = vecs[768 + f0],  cz2b = vecs[768 + f1];
    const float cr2a = vecs[896 + f0],  cr2b = vecs[896 + f1];
    const float ch2a = vecs[1024 + f0], ch2b = vecs[1024 + f1];

    __syncthreads();

    const float* xb = x + (size_t)b * (TSTEPS * NN);
    if (t < NROW) {  // sax for step 0 (pad rows -> 0 since A pad rows are zero)
        float a = 0.0f;
        for (int j = 0; j < NN; j++) a = fmaf(sA[t * NN + j], xb[j], a);
        sax[0][t] = a;
    }
    __syncthreads();

    double oacc0 = 0.0, oacc1 = 0.0;

    for (int step = 0; step < TSTEPS; step++) {
        const int pb = step & 1;
        float ax[RPT];
        #pragma unroll
        for (int r = 0; r < RPT; r++) ax[r] = sax[pb][iA + r];

        // ---------- P1: layer-1 z,r gates (dist-1 pipelined) ----------
        float az0[RPT], az1[RPT], ar0[RPT], ar1[RPT];
        #pragma unroll
        for (int r = 0; r < RPT; r++) {
            az0[r] = fmaf(ax[r], wz1a, cz1a);
            az1[r] = fmaf(ax[r], wz1b, cz1b);
            ar0[r] = fmaf(ax[r], wr1a, cr1a);
            ar1[r] = fmaf(ax[r], wr1b, cr1b);
        }
        {
            float4 wz0c = Lzr1[f0], wz1c = Lzr1[f1];
            float4 wr0c = Lzr1[128 + f0], wr1c = Lzr1[128 + f1];
            float4 hc[RPT];
            #pragma unroll
            for (int r = 0; r < RPT; r++) hc[r] = H1v[(iA + r) * 32];
            #pragma unroll 2
            for (int c = 0; c < 32; ++c) {
                const int cn = (c + 1) & 31;
                float4 wz0n = Lzr1[cn * 256 + f0], wz1n = Lzr1[cn * 256 + f1];
                float4 wr0n = Lzr1[cn * 256 + 128 + f0], wr1n = Lzr1[cn * 256 + 128 + f1];
                float4 hn[RPT];
                #pragma unroll
                for (int r = 0; r < RPT; r++) hn[r] = H1v[(iA + r) * 32 + cn];
                #pragma unroll
                for (int r = 0; r < RPT; r++) {
                    az0[r] = fma4(hc[r], wz0c, az0[r]);
                    az1[r] = fma4(hc[r], wz1c, az1[r]);
                    ar0[r] = fma4(hc[r], wr0c, ar0[r]);
                    ar1[r] = fma4(hc[r], wr1c, ar1[r]);
                }
                wz0c = wz0n; wz1c = wz1n; wr0c = wr0n; wr1c = wr1n;
                #pragma unroll
                for (int r = 0; r < RPT; r++) hc[r] = hn[r];
            }
        }
        float z0[RPT], z1[RPT], h1c0[RPT], h1c1[RPT];
        #pragma unroll
        for (int r = 0; r < RPT; r++) {
            z0[r] = sigmoidf(az0[r]);
            z1[r] = sigmoidf(az1[r]);
            const float r0 = sigmoidf(ar0[r]);
            const float r1 = sigmoidf(ar1[r]);
            h1c0[r] = sH1[(iA + r) * HID + f0];
            h1c1[r] = sH1[(iA + r) * HID + f1];
            sHR[(iA + r) * HID + f0] = h1c0[r] * r0;
            sHR[(iA + r) * HID + f1] = h1c1[r] * r1;
        }
        WAVE_SYNC();   // intra-wave only: P2 reads this wave's own HR rows

        // ---------- P2: layer-1 h gate + H1 update (dist-1 pipelined) ----------
        float ah0[RPT], ah1[RPT];
        #pragma unroll
        for (int r = 0; r < RPT; r++) {
            ah0[r] = fmaf(ax[r], wh1a, ch1a);
            ah1[r] = fmaf(ax[r], wh1b, ch1b);
        }
        {
            float4 wh0c = Lh1[f0], wh1c = Lh1[f1];
            float4 qc[RPT];
            #pragma unroll
            for (int r = 0; r < RPT; r++) qc[r] = HRv[(iA + r) * 32];
            #pragma unroll 2
            for (int c = 0; c < 32; ++c) {
                const int cn = (c + 1) & 31;
                float4 wh0n = Lh1[cn * 128 + f0], wh1n = Lh1[cn * 128 + f1];
                float4 qn[RPT];
                #pragma unroll
                for (int r = 0; r < RPT; r++) qn[r] = HRv[(iA + r) * 32 + cn];
                #pragma unroll
                for (int r = 0; r < RPT; r++) {
                    ah0[r] = fma4(qc[r], wh0c, ah0[r]);
                    ah1[r] = fma4(qc[r], wh1c, ah1[r]);
                }
                wh0c = wh0n; wh1c = wh1n;
                #pragma unroll
                for (int r = 0; r < RPT; r++) qc[r] = qn[r];
            }
        }
        #pragma unroll
        for (int r = 0; r < RPT; r++) {
            const float n0 = fmaf(z0[r], h1c0[r], (1.0f - z0[r]) * tanhf(ah0[r]));
            const float n1 = fmaf(z1[r], h1c1[r], (1.0f - z1[r]) * tanhf(ah1[r]));
            sH1[(iA + r) * HID + f0] = n0;
            sH1[(iA + r) * HID + f1] = n1;
        }
        __syncthreads();   // B1: P3 reads ALL rows of H1 (cross-wave)

        // ---------- P3: AH1 = A @ H1 ----------
        {
            float aa0[RPT], aa1[RPT];
            #pragma unroll
            for (int r = 0; r < RPT; r++) { aa0[r] = 0.0f; aa1[r] = 0.0f; }
            #pragma unroll 3
            for (int j = 0; j < NN; j++) {
                const float hj0 = sH1[j * HID + f0];
                const float hj1 = sH1[j * HID + f1];
                #pragma unroll
                for (int r = 0; r < RPT; r++) {
                    const float arj = sA[(iA + r) * NN + j];
                    aa0[r] = fmaf(arj, hj0, aa0[r]);
                    aa1[r] = fmaf(arj, hj1, aa1[r]);
                }
            }
            #pragma unroll
            for (int r = 0; r < RPT; r++) {
                sAH[(iA + r) * HID + f0] = aa0[r];
                sAH[(iA + r) * HID + f1] = aa1[r];
            }
        }
        WAVE_SYNC();   // intra-wave only: P4 reads this wave's own AH rows

        // ---------- P4: layer-2 gcn + z,r gates (weights dist-1 pipelined) ----------
        float pz0[RPT], pz1[RPT], pr0[RPT], pr1[RPT], ph0[RPT], ph1[RPT];
        #pragma unroll
        for (int r = 0; r < RPT; r++) {
            pz0[r] = cz2a; pz1[r] = cz2b;
            pr0[r] = cr2a; pr1[r] = cr2b;
            ph0[r] = ch2a; ph1[r] = ch2b;
        }
        {
            float4 wz0c = We2[f0], wz1c = We2[f1];
            float4 wr0c = We2[128 + f0], wr1c = We2[128 + f1];
            float4 wh0c = We2[256 + f0], wh1c = We2[256 + f1];
            float4 lz0c = Lzr2[f0], lz1c = Lzr2[f1];
            float4 lr0c = Lzr2[128 + f0], lr1c = Lzr2[128 + f1];
            #pragma unroll 2
            for (int c = 0; c < 32; ++c) {
                const int cn = (c + 1) & 31;
                float4 wz0n = We2[cn * 384 + f0], wz1n = We2[cn * 384 + f1];
                float4 wr0n = We2[cn * 384 + 128 + f0], wr1n = We2[cn * 384 + 128 + f1];
                float4 wh0n = We2[cn * 384 + 256 + f0], wh1n = We2[cn * 384 + 256 + f1];
                float4 lz0n = Lzr2[cn * 256 + f0], lz1n = Lzr2[cn * 256 + f1];
                float4 lr0n = Lzr2[cn * 256 + 128 + f0], lr1n = Lzr2[cn * 256 + 128 + f1];
                #pragma unroll
                for (int r = 0; r < RPT; r++) {
                    const float4 a = AHv[(iA + r) * 32 + c];
                    const float4 q = H2v[(iA + r) * 32 + c];
                    // per-element order: a-chunk then g-chunk per c (matches round 4)
                    pz0[r] = fma4(a, wz0c, pz0[r]); pz0[r] = fma4(q, lz0c, pz0[r]);
                    pz1[r] = fma4(a, wz1c, pz1[r]); pz1[r] = fma4(q, lz1c, pz1[r]);
                    pr0[r] = fma4(a, wr0c, pr0[r]); pr0[r] = fma4(q, lr0c, pr0[r]);
                    pr1[r] = fma4(a, wr1c, pr1[r]); pr1[r] = fma4(q, lr1c, pr1[r]);
                    ph0[r] = fma4(a, wh0c, ph0[r]);
                    ph1[r] = fma4(a, wh1c, ph1[r]);
                }
                wz0c = wz0n; wz1c = wz1n; wr0c = wr0n; wr1c = wr1n;
                wh0c = wh0n; wh1c = wh1n;
                lz0c = lz0n; lz1c = lz1n; lr0c = lr0n; lr1c = lr1n;
            }
        }
        float z20[RPT], z21[RPT], h2c0[RPT], h2c1[RPT];
        #pragma unroll
        for (int r = 0; r < RPT; r++) {
            z20[r] = sigmoidf(pz0[r]);
            z21[r] = sigmoidf(pz1[r]);
            const float r20 = sigmoidf(pr0[r]);
            const float r21 = sigmoidf(pr1[r]);
            h2c0[r] = sH2[(iA + r) * HID + f0];
            h2c1[r] = sH2[(iA + r) * HID + f1];
            sHR[(iA + r) * HID + f0] = h2c0[r] * r20;
            sHR[(iA + r) * HID + f1] = h2c1[r] * r21;
        }
        WAVE_SYNC();   // intra-wave only: P5 reads this wave's own HR rows

        // ---------- P5: layer-2 h gate + H2 update + output accum ----------
        {
            float4 lh0c = Lh2[f0], lh1c = Lh2[f1];
            float4 qc[RPT];
            #pragma unroll
            for (int r = 0; r < RPT; r++) qc[r] = HRv[(iA + r) * 32];
            #pragma unroll 2
            for (int c = 0; c < 32; ++c) {
                const int cn = (c + 1) & 31;
                float4 lh0n = Lh2[cn * 128 + f0], lh1n = Lh2[cn * 128 + f1];
                float4 qn[RPT];
                #pragma unroll
                for (int r = 0; r < RPT; r++) qn[r] = HRv[(iA + r) * 32 + cn];
                #pragma unroll
                for (int r = 0; r < RPT; r++) {
                    ph0[r] = fma4(qc[r], lh0c, ph0[r]);
                    ph1[r] = fma4(qc[r], lh1c, ph1[r]);
                }
                lh0c = lh0n; lh1c = lh1n;
                #pragma unroll
                for (int r = 0; r < RPT; r++) qc[r] = qn[r];
            }
        }
        #pragma unroll
        for (int r = 0; r < RPT; r++) {
            const float m0 = fmaf(z20[r], h2c0[r], (1.0f - z20[r]) * tanhf(ph0[r]));
            const float m1 = fmaf(z21[r], h2c1[r], (1.0f - z21[r]) * tanhf(ph1[r]));
            sH2[(iA + r) * HID + f0] = m0;
            sH2[(iA + r) * HID + f1] = m1;
            if (r < nreal) {            // wave-uniform: exclude pad rows
                oacc0 += (double)m0;
                oacc1 += (double)m1;
            }
        }

        // prefetch next step's ax (threads 0..23; pad rows -> 0)
        if (step + 1 < TSTEPS && t < NROW) {
            const float* xt = xb + (step + 1) * NN;
            float a = 0.0f;
            for (int j = 0; j < NN; j++) a = fmaf(sA[t * NN + j], xt[j], a);
            sax[(step + 1) & 1][t] = a;
        }
        __syncthreads();   // B2: sax (wave 0) -> all waves; H1 epoch boundary
    }

    // ---------- Epilogue: mean over (T, nodes), dot with cls_w ----------
    sred[g][f0] = oacc0;
    sred[g][f1] = oacc1;
    __syncthreads();
    if (t < HID) {
        double s = 0.0;
        for (int gg = 0; gg < 4; gg++) s += sred[gg][t];
        sred[0][t] = (s / (double)(TSTEPS * NN)) * (double)cls_w[t];
    }
    __syncthreads();
    if (t < 64) {
        double v = ((double*)sred)[t] + ((double*)sred)[t + 64];
        for (int off = 32; off; off >>= 1) v += __shfl_down(v, off, 64);
        if (t == 0) out[b] = (float)(v + (double)cls_b[0]);
    }
}

extern "C" void kernel_launch(void* const* d_in, const int* in_sizes, int n_in,
                              void* d_out, int out_size, void* d_ws, size_t ws_size,
                              hipStream_t stream) {
    const float* x    = (const float*)d_in[0];
    const int*   ei   = (const int*)  d_in[1];
    const float* ew   = (const float*)d_in[2];
    const float* Wz1  = (const float*)d_in[3];
    const float* bz1  = (const float*)d_in[4];
    const float* lzw1 = (const float*)d_in[5];
    const float* lzb1 = (const float*)d_in[6];
    const float* Wr1  = (const float*)d_in[7];
    const float* br1  = (const float*)d_in[8];
    const float* lrw1 = (const float*)d_in[9];
    const float* lrb1 = (const float*)d_in[10];
    const float* Wh1  = (const float*)d_in[11];
    const float* bh1  = (const float*)d_in[12];
    const float* lhw1 = (const float*)d_in[13];
    const float* lhb1 = (const float*)d_in[14];
    const float* Wz2  = (const float*)d_in[15];
    const float* bz2  = (const float*)d_in[16];
    const float* lzw2 = (const float*)d_in[17];
    const float* lzb2 = (const float*)d_in[18];
    const float* Wr2  = (const float*)d_in[19];
    const float* br2  = (const float*)d_in[20];
    const float* lrw2 = (const float*)d_in[21];
    const float* lrb2 = (const float*)d_in[22];
    const float* Wh2  = (const float*)d_in[23];
    const float* bh2  = (const float*)d_in[24];
    const float* lhw2 = (const float*)d_in[25];
    const float* lhb2 = (const float*)d_in[26];
    const float* clsw = (const float*)d_in[27];
    const float* clsb = (const float*)d_in[28];

    float* ws   = (float*)d_ws;
    float* outp = (float*)d_out;

    build_A<<<1, 64, 0, stream>>>(ei, ew, ws + WS_A);
    pack_bot<<<32, 256, 0, stream>>>(lzw1, lrw1, (float4*)(ws + WS_LZR1), 2);
    pack_bot<<<16, 256, 0, stream>>>(lhw1, lhw1, (float4*)(ws + WS_LH1), 1);
    pack_bot<<<32, 256, 0, stream>>>(lzw2, lrw2, (float4*)(ws + WS_LZR2), 2);
    pack_bot<<<16, 256, 0, stream>>>(lhw2, lhw2, (float4*)(ws + WS_LH2), 1);
    make_weff2<<<48, 256, 0, stream>>>(Wz2, Wr2, Wh2, lzw2, lrw2, lhw2,
                                       (float4*)(ws + WS_WE2));
    make_vecs<<<5, 256, 0, stream>>>(Wz1, Wr1, Wh1, bz1, br1, bh1,
                                     lzw1, lrw1, lhw1, lzb1, lrb1, lhb1,
                                     bz2, br2, bh2, lzw2, lrw2, lhw2,
                                     lzb2, lrb2, lhb2, ws + WS_VEC);
    tgcn_main<<<64, NTHREADS, 0, stream>>>(x, ws, clsw, clsb, outp);
}

// Round 6
// 14985.399 us; speedup vs baseline: 1.3132x; 1.3132x over previous
//
#include <hip/hip_runtime.h>
#include <hip/hip_bf16.h>

// TGCN: B=64, T=500, N=21, HID=128.
// Round 6: layer-pipelined wave groups. One block per batch (64 x 512 thr).
//   Group A = waves 0..3: layer-1 of step k+1 (P1,P2 -> H1; phase2 P3 -> AH
//             double-buffer + sax prefetch). 192 KB weights/wave/step.
//   Group B = waves 4..7: layer-2 of step k (P4,P5 + output accum) reading
//             AH[k&1]. 384 KB weights/wave/step.
// Same total weight traffic / FMAs as round 4, but 2 waves/SIMD so one
// group's FMA bursts cover the other's load stalls (round-4/5 showed a
// single wave/SIMD serializes: time ~= sum of pipes, not max).
// Every dot product keeps BIT-IDENTICAL accumulation order to round 4
// (c ascending, fma4 x..w, a-then-g chunk in P4; same oacc/epilogue
// grouping). Never reorder sums in the recurrence — threshold is thin.

#define NN 21
#define NROW 24            // padded rows (21,22,23 zero)
#define HID 128
#define TSTEPS 500
#define EDGES 210
#define NTHREADS 512       // 8 waves: 4 per group
#define RPT 6              // rows per thread (within a group)

// ws layout (float offsets)
#define WS_A     0        // NROW*NN floats (pad rows zeroed on build)
#define WS_VEC   1600     // 9*128
#define WS_LZR1  3200     // 32*256*4
#define WS_LH1   36000    // 32*128*4
#define WS_WE2   52400    // 32*384*4
#define WS_LZR2  101600   // 32*256*4
#define WS_LH2   134400   // 32*128*4

// Wave-local LDS release (intra-wave producer->consumer through LDS).
#define WAVE_SYNC() asm volatile("s_waitcnt lgkmcnt(0)" ::: "memory")

__device__ __forceinline__ float fma4(float4 a, float4 b, float acc) {
    acc = fmaf(a.x, b.x, acc);
    acc = fmaf(a.y, b.y, acc);
    acc = fmaf(a.z, b.z, acc);
    acc = fmaf(a.w, b.w, acc);
    return acc;
}

__device__ __forceinline__ float sigmoidf(float v) {
    return 1.0f / (1.0f + expf(-v));
}

// ---- Prologue: build normalized adjacency A (21x21) in fp64, store fp32 ----
__global__ void build_A(const int* __restrict__ ei, const float* __restrict__ ew,
                        float* __restrict__ Aout) {
    __shared__ double deg[NN];
    __shared__ double dinv[NN];
    __shared__ double Asm[NN * NN];
    int t = threadIdx.x;
    for (int k = t; k < NN * NN; k += blockDim.x) Asm[k] = 0.0;
    if (t < NN) deg[t] = 1.0;  // self loop weight 1
    __syncthreads();
    if (t == 0) {
        for (int e = 0; e < EDGES; e++) deg[ei[EDGES + e]] += (double)ew[e];
        for (int i = 0; i < NN; i++) dinv[i] = deg[i] > 0.0 ? 1.0 / sqrt(deg[i]) : 0.0;
        for (int e = 0; e < EDGES; e++) {
            int s = ei[e], d = ei[EDGES + e];
            Asm[d * NN + s] += dinv[s] * (double)ew[e] * dinv[d];
        }
        for (int i = 0; i < NN; i++) Asm[i * NN + i] += dinv[i] * dinv[i];
    }
    __syncthreads();
    for (int k = t; k < NROW * NN; k += blockDim.x)
        Aout[k] = (k < NN * NN) ? (float)Asm[k] : 0.0f;
}

// ---- Prologue: repack bottom halves of (256,128) concat weights ----
__global__ void pack_bot(const float* __restrict__ w0, const float* __restrict__ w1,
                         float4* __restrict__ out, int ngate) {
    int t = blockIdx.x * blockDim.x + threadIdx.x;
    int ncol = ngate * 128;
    int total = 32 * ncol;
    if (t >= total) return;
    int c = t / ncol, col = t - c * ncol;
    const float* src = (col < 128) ? w0 : w1;
    int f = col & 127;
    int k = 4 * c;
    float4 v;
    v.x = src[(128 + k + 0) * 128 + f];
    v.y = src[(128 + k + 1) * 128 + f];
    v.z = src[(128 + k + 2) * 128 + f];
    v.w = src[(128 + k + 3) * 128 + f];
    out[t] = v;
}

// ---- Prologue: Weff2_g = Wg_2 @ lgw_2_top, packed [c][g*128+f], fp64 accum ----
__global__ void make_weff2(const float* __restrict__ Wz2, const float* __restrict__ Wr2,
                           const float* __restrict__ Wh2,
                           const float* __restrict__ lzw2, const float* __restrict__ lrw2,
                           const float* __restrict__ lhw2,
                           float4* __restrict__ out) {
    int t = blockIdx.x * blockDim.x + threadIdx.x;  // [0, 32*384)
    if (t >= 32 * 384) return;
    int c = t / 384, col = t - c * 384;
    int g = col >> 7, f = col & 127;
    const float* W = (g == 0) ? Wz2 : (g == 1) ? Wr2 : Wh2;
    const float* L = (g == 0) ? lzw2 : (g == 1) ? lrw2 : lhw2;
    double a0 = 0, a1 = 0, a2 = 0, a3 = 0;
    for (int m = 0; m < 128; m++) {
        double lm = (double)L[m * 128 + f];
        a0 += (double)W[(4 * c + 0) * 128 + m] * lm;
        a1 += (double)W[(4 * c + 1) * 128 + m] * lm;
        a2 += (double)W[(4 * c + 2) * 128 + m] * lm;
        a3 += (double)W[(4 * c + 3) * 128 + m] * lm;
    }
    out[t] = make_float4((float)a0, (float)a1, (float)a2, (float)a3);
}

// ---- Prologue: layer-1 effective row vectors + all bias consts (fp64) ----
__global__ void make_vecs(const float* __restrict__ Wz1, const float* __restrict__ Wr1,
                          const float* __restrict__ Wh1,
                          const float* __restrict__ bz1, const float* __restrict__ br1,
                          const float* __restrict__ bh1,
                          const float* __restrict__ lzw1, const float* __restrict__ lrw1,
                          const float* __restrict__ lhw1,
                          const float* __restrict__ lzb1, const float* __restrict__ lrb1,
                          const float* __restrict__ lhb1,
                          const float* __restrict__ bz2, const float* __restrict__ br2,
                          const float* __restrict__ bh2,
                          const float* __restrict__ lzw2, const float* __restrict__ lrw2,
                          const float* __restrict__ lhw2,
                          const float* __restrict__ lzb2, const float* __restrict__ lrb2,
                          const float* __restrict__ lhb2,
                          float* __restrict__ out) {
    int t = blockIdx.x * blockDim.x + threadIdx.x;
    if (t >= 9 * 128) return;
    int v = t >> 7, f = t & 127;
    double acc = 0.0;
    if (v < 3) {
        const float* W = (v == 0) ? Wz1 : (v == 1) ? Wr1 : Wh1;   // (1,128)
        const float* L = (v == 0) ? lzw1 : (v == 1) ? lrw1 : lhw1;
        for (int m = 0; m < 128; m++) acc += (double)W[m] * (double)L[m * 128 + f];
    } else if (v < 6) {
        int g = v - 3;
        const float* bb = (g == 0) ? bz1 : (g == 1) ? br1 : bh1;
        const float* L  = (g == 0) ? lzw1 : (g == 1) ? lrw1 : lhw1;
        const float* lb = (g == 0) ? lzb1 : (g == 1) ? lrb1 : lhb1;
        for (int m = 0; m < 128; m++) acc += (double)bb[m] * (double)L[m * 128 + f];
        acc += (double)lb[f];
    } else {
        int g = v - 6;
        const float* bb = (g == 0) ? bz2 : (g == 1) ? br2 : bh2;
        const float* L  = (g == 0) ? lzw2 : (g == 1) ? lrw2 : lhw2;
        const float* lb = (g == 0) ? lzb2 : (g == 1) ? lrb2 : lhb2;
        for (int m = 0; m < 128; m++) acc += (double)bb[m] * (double)L[m * 128 + f];
        acc += (double)lb[f];
    }
    out[t] = (float)acc;
}

// ---- Main: one block per batch element, layer-pipelined wave groups ----
__global__ __launch_bounds__(NTHREADS, 2) void tgcn_main(
    const float* __restrict__ x,       // (64,500,21)
    const float* __restrict__ ws,
    const float* __restrict__ cls_w,   // (128,1)
    const float* __restrict__ cls_b,   // (1,)
    float* __restrict__ out)           // (64,)
{
    const int b  = blockIdx.x;
    const int t  = threadIdx.x;
    const bool isA = (t < 256);                              // wave-uniform
    const int lt = t & 255;
    const int f0 = lt & 63;
    const int f1 = f0 + 64;
    const int gw = __builtin_amdgcn_readfirstlane(lt >> 6);  // 0..3 in group
    const int iA = gw * RPT;                                 // first owned row
    const int nreal = (iA + RPT <= NN) ? RPT : (NN - iA);

    __shared__ __align__(16) float sH1[NROW * HID];
    __shared__ __align__(16) float sH2[NROW * HID];
    __shared__ __align__(16) float sHR1[NROW * HID];
    __shared__ __align__(16) float sHR2[NROW * HID];
    __shared__ __align__(16) float sAH[2][NROW * HID];
    __shared__ float sA[NROW * NN];    // pad rows zero
    __shared__ float sax[2][NROW];
    __shared__ double sred[4][HID];

    const float*  vecs = ws + WS_VEC;
    const float4* Lzr1 = (const float4*)(ws + WS_LZR1);
    const float4* Lh1  = (const float4*)(ws + WS_LH1);
    const float4* We2  = (const float4*)(ws + WS_WE2);
    const float4* Lzr2 = (const float4*)(ws + WS_LZR2);
    const float4* Lh2  = (const float4*)(ws + WS_LH2);

    const float4* H1v  = (const float4*)sH1;   // row stride 32 float4
    const float4* H2v  = (const float4*)sH2;
    const float4* HR1v = (const float4*)sHR1;
    const float4* HR2v = (const float4*)sHR2;

    for (int k = t; k < NROW * HID; k += NTHREADS) { sH1[k] = 0.0f; sH2[k] = 0.0f; }
    for (int k = t; k < NROW * NN; k += NTHREADS) sA[k] = ws[WS_A + k];

    // layer-1 consts (used by A) and layer-2 consts (used by B)
    const float wz1a = vecs[f0],        wz1b = vecs[f1];
    const float wr1a = vecs[128 + f0],  wr1b = vecs[128 + f1];
    const float wh1a = vecs[256 + f0],  wh1b = vecs[256 + f1];
    const float cz1a = vecs[384 + f0],  cz1b = vecs[384 + f1];
    const float cr1a = vecs[512 + f0],  cr1b = vecs[512 + f1];
    const float ch1a = vecs[640 + f0],  ch1b = vecs[640 + f1];
    const float cz2a = vecs[768 + f0],  cz2b = vecs[768 + f1];
    const float cr2a = vecs[896 + f0],  cr2b = vecs[896 + f1];
    const float ch2a = vecs[1024 + f0], ch2b = vecs[1024 + f1];

    __syncthreads();

    const float* xb = x + (size_t)b * (TSTEPS * NN);
    if (t < NROW) {  // sax for steps 0 and 1 (pad rows -> 0: A pad rows zero)
        float a0s = 0.0f, a1s = 0.0f;
        for (int j = 0; j < NN; j++) {
            a0s = fmaf(sA[t * NN + j], xb[j], a0s);
            a1s = fmaf(sA[t * NN + j], xb[NN + j], a1s);
        }
        sax[0][t] = a0s;
        sax[1][t] = a1s;
    }
    __syncthreads();

    double oacc0 = 0.0, oacc1 = 0.0;   // group B only

    // ================= pipeline prologue: A computes step 0 =================
    if (isA) {
        const float ax0s = sax[0][iA + 0], ax1s = sax[0][iA + 1], ax2s = sax[0][iA + 2];
        const float ax3s = sax[0][iA + 3], ax4s = sax[0][iA + 4], ax5s = sax[0][iA + 5];
        float axp[RPT] = {ax0s, ax1s, ax2s, ax3s, ax4s, ax5s};
        // P1
        float az0[RPT], az1[RPT], ar0[RPT], ar1[RPT];
        #pragma unroll
        for (int r = 0; r < RPT; r++) {
            az0[r] = fmaf(axp[r], wz1a, cz1a);
            az1[r] = fmaf(axp[r], wz1b, cz1b);
            ar0[r] = fmaf(axp[r], wr1a, cr1a);
            ar1[r] = fmaf(axp[r], wr1b, cr1b);
        }
        #pragma unroll 2
        for (int c = 0; c < 32; ++c) {
            const float4 wz0 = Lzr1[c * 256 + f0];
            const float4 wz1 = Lzr1[c * 256 + f1];
            const float4 wr0 = Lzr1[c * 256 + 128 + f0];
            const float4 wr1 = Lzr1[c * 256 + 128 + f1];
            #pragma unroll
            for (int r = 0; r < RPT; r++) {
                const float4 h = H1v[(iA + r) * 32 + c];
                az0[r] = fma4(h, wz0, az0[r]);
                az1[r] = fma4(h, wz1, az1[r]);
                ar0[r] = fma4(h, wr0, ar0[r]);
                ar1[r] = fma4(h, wr1, ar1[r]);
            }
        }
        float z0[RPT], z1[RPT], h1c0[RPT], h1c1[RPT];
        #pragma unroll
        for (int r = 0; r < RPT; r++) {
            z0[r] = sigmoidf(az0[r]);
            z1[r] = sigmoidf(az1[r]);
            const float r0 = sigmoidf(ar0[r]);
            const float r1 = sigmoidf(ar1[r]);
            h1c0[r] = sH1[(iA + r) * HID + f0];
            h1c1[r] = sH1[(iA + r) * HID + f1];
            sHR1[(iA + r) * HID + f0] = h1c0[r] * r0;
            sHR1[(iA + r) * HID + f1] = h1c1[r] * r1;
        }
        WAVE_SYNC();
        // P2
        float ah0[RPT], ah1[RPT];
        #pragma unroll
        for (int r = 0; r < RPT; r++) {
            ah0[r] = fmaf(axp[r], wh1a, ch1a);
            ah1[r] = fmaf(axp[r], wh1b, ch1b);
        }
        #pragma unroll 2
        for (int c = 0; c < 32; ++c) {
            const float4 wh0 = Lh1[c * 128 + f0];
            const float4 wh1 = Lh1[c * 128 + f1];
            #pragma unroll
            for (int r = 0; r < RPT; r++) {
                const float4 q = HR1v[(iA + r) * 32 + c];
                ah0[r] = fma4(q, wh0, ah0[r]);
                ah1[r] = fma4(q, wh1, ah1[r]);
            }
        }
        #pragma unroll
        for (int r = 0; r < RPT; r++) {
            const float n0 = fmaf(z0[r], h1c0[r], (1.0f - z0[r]) * tanhf(ah0[r]));
            const float n1 = fmaf(z1[r], h1c1[r], (1.0f - z1[r]) * tanhf(ah1[r]));
            sH1[(iA + r) * HID + f0] = n0;
            sH1[(iA + r) * HID + f1] = n1;
        }
    }
    __syncthreads();
    if (isA) {  // P3 for step 0 -> AH buf 0
        float aa0[RPT], aa1[RPT];
        #pragma unroll
        for (int r = 0; r < RPT; r++) { aa0[r] = 0.0f; aa1[r] = 0.0f; }
        #pragma unroll 3
        for (int j = 0; j < NN; j++) {
            const float hj0 = sH1[j * HID + f0];
            const float hj1 = sH1[j * HID + f1];
            #pragma unroll
            for (int r = 0; r < RPT; r++) {
                const float arj = sA[(iA + r) * NN + j];
                aa0[r] = fmaf(arj, hj0, aa0[r]);
                aa1[r] = fmaf(arj, hj1, aa1[r]);
            }
        }
        #pragma unroll
        for (int r = 0; r < RPT; r++) {
            sAH[0][(iA + r) * HID + f0] = aa0[r];
            sAH[0][(iA + r) * HID + f1] = aa1[r];
        }
    }
    __syncthreads();

    // ================= main ticks: A does step k+1, B does step k ============
    for (int k = 0; k < TSTEPS; k++) {
        // ---------------- phase 1 ----------------
        if (isA) {
            if (k < TSTEPS - 1) {
                const int sp = (k + 1) & 1;
                float axp[RPT];
                #pragma unroll
                for (int r = 0; r < RPT; r++) axp[r] = sax[sp][iA + r];
                // P1
                float az0[RPT], az1[RPT], ar0[RPT], ar1[RPT];
                #pragma unroll
                for (int r = 0; r < RPT; r++) {
                    az0[r] = fmaf(axp[r], wz1a, cz1a);
                    az1[r] = fmaf(axp[r], wz1b, cz1b);
                    ar0[r] = fmaf(axp[r], wr1a, cr1a);
                    ar1[r] = fmaf(axp[r], wr1b, cr1b);
                }
                #pragma unroll 2
                for (int c = 0; c < 32; ++c) {
                    const float4 wz0 = Lzr1[c * 256 + f0];
                    const float4 wz1 = Lzr1[c * 256 + f1];
                    const float4 wr0 = Lzr1[c * 256 + 128 + f0];
                    const float4 wr1 = Lzr1[c * 256 + 128 + f1];
                    #pragma unroll
                    for (int r = 0; r < RPT; r++) {
                        const float4 h = H1v[(iA + r) * 32 + c];
                        az0[r] = fma4(h, wz0, az0[r]);
                        az1[r] = fma4(h, wz1, az1[r]);
                        ar0[r] = fma4(h, wr0, ar0[r]);
                        ar1[r] = fma4(h, wr1, ar1[r]);
                    }
                }
                float z0[RPT], z1[RPT], h1c0[RPT], h1c1[RPT];
                #pragma unroll
                for (int r = 0; r < RPT; r++) {
                    z0[r] = sigmoidf(az0[r]);
                    z1[r] = sigmoidf(az1[r]);
                    const float r0 = sigmoidf(ar0[r]);
                    const float r1 = sigmoidf(ar1[r]);
                    h1c0[r] = sH1[(iA + r) * HID + f0];
                    h1c1[r] = sH1[(iA + r) * HID + f1];
                    sHR1[(iA + r) * HID + f0] = h1c0[r] * r0;
                    sHR1[(iA + r) * HID + f1] = h1c1[r] * r1;
                }
                WAVE_SYNC();
                // P2
                float ah0[RPT], ah1[RPT];
                #pragma unroll
                for (int r = 0; r < RPT; r++) {
                    ah0[r] = fmaf(axp[r], wh1a, ch1a);
                    ah1[r] = fmaf(axp[r], wh1b, ch1b);
                }
                #pragma unroll 2
                for (int c = 0; c < 32; ++c) {
                    const float4 wh0 = Lh1[c * 128 + f0];
                    const float4 wh1 = Lh1[c * 128 + f1];
                    #pragma unroll
                    for (int r = 0; r < RPT; r++) {
                        const float4 q = HR1v[(iA + r) * 32 + c];
                        ah0[r] = fma4(q, wh0, ah0[r]);
                        ah1[r] = fma4(q, wh1, ah1[r]);
                    }
                }
                #pragma unroll
                for (int r = 0; r < RPT; r++) {
                    const float n0 = fmaf(z0[r], h1c0[r], (1.0f - z0[r]) * tanhf(ah0[r]));
                    const float n1 = fmaf(z1[r], h1c1[r], (1.0f - z1[r]) * tanhf(ah1[r]));
                    sH1[(iA + r) * HID + f0] = n0;
                    sH1[(iA + r) * HID + f1] = n1;
                }
            }
        } else {
            // ----- group B: layer-2 for step k -----
            const float* AHf = sAH[k & 1];
            const float4* AHv = (const float4*)AHf;
            // P4
            float pz0[RPT], pz1[RPT], pr0[RPT], pr1[RPT], ph0[RPT], ph1[RPT];
            #pragma unroll
            for (int r = 0; r < RPT; r++) {
                pz0[r] = cz2a; pz1[r] = cz2b;
                pr0[r] = cr2a; pr1[r] = cr2b;
                ph0[r] = ch2a; ph1[r] = ch2b;
            }
            for (int c = 0; c < 32; ++c) {
                const float4 wz0 = We2[c * 384 + f0];
                const float4 wz1 = We2[c * 384 + f1];
                const float4 wr0 = We2[c * 384 + 128 + f0];
                const float4 wr1 = We2[c * 384 + 128 + f1];
                const float4 wh0 = We2[c * 384 + 256 + f0];
                const float4 wh1 = We2[c * 384 + 256 + f1];
                const float4 lz0 = Lzr2[c * 256 + f0];
                const float4 lz1 = Lzr2[c * 256 + f1];
                const float4 lr0 = Lzr2[c * 256 + 128 + f0];
                const float4 lr1 = Lzr2[c * 256 + 128 + f1];
                #pragma unroll
                for (int r = 0; r < RPT; r++) {
                    const float4 a = AHv[(iA + r) * 32 + c];
                    const float4 q = H2v[(iA + r) * 32 + c];
                    // per-element order: a-chunk then g-chunk per c (round 4)
                    pz0[r] = fma4(a, wz0, pz0[r]); pz0[r] = fma4(q, lz0, pz0[r]);
                    pz1[r] = fma4(a, wz1, pz1[r]); pz1[r] = fma4(q, lz1, pz1[r]);
                    pr0[r] = fma4(a, wr0, pr0[r]); pr0[r] = fma4(q, lr0, pr0[r]);
                    pr1[r] = fma4(a, wr1, pr1[r]); pr1[r] = fma4(q, lr1, pr1[r]);
                    ph0[r] = fma4(a, wh0, ph0[r]);
                    ph1[r] = fma4(a, wh1, ph1[r]);
                }
            }
            float z20[RPT], z21[RPT], h2c0[RPT], h2c1[RPT];
            #pragma unroll
            for (int r = 0; r < RPT; r++) {
                z20[r] = sigmoidf(pz0[r]);
                z21[r] = sigmoidf(pz1[r]);
                const float r20 = sigmoidf(pr0[r]);
                const float r21 = sigmoidf(pr1[r]);
                h2c0[r] = sH2[(iA + r) * HID + f0];
                h2c1[r] = sH2[(iA + r) * HID + f1];
                sHR2[(iA + r) * HID + f0] = h2c0[r] * r20;
                sHR2[(iA + r) * HID + f1] = h2c1[r] * r21;
            }
            WAVE_SYNC();
            // P5
            #pragma unroll 2
            for (int c = 0; c < 32; ++c) {
                const float4 lh0 = Lh2[c * 128 + f0];
                const float4 lh1 = Lh2[c * 128 + f1];
                #pragma unroll
                for (int r = 0; r < RPT; r++) {
                    const float4 q = HR2v[(iA + r) * 32 + c];
                    ph0[r] = fma4(q, lh0, ph0[r]);
                    ph1[r] = fma4(q, lh1, ph1[r]);
                }
            }
            #pragma unroll
            for (int r = 0; r < RPT; r++) {
                const float m0 = fmaf(z20[r], h2c0[r], (1.0f - z20[r]) * tanhf(ph0[r]));
                const float m1 = fmaf(z21[r], h2c1[r], (1.0f - z21[r]) * tanhf(ph1[r]));
                sH2[(iA + r) * HID + f0] = m0;
                sH2[(iA + r) * HID + f1] = m1;
                if (r < nreal) {            // wave-uniform: exclude pad rows
                    oacc0 += (double)m0;
                    oacc1 += (double)m1;
                }
            }
        }
        __syncthreads();   // S1: H1(k+1) complete (A), HR2/H2 done (B)

        // ---------------- phase 2 (A only; B falls through) ----------------
        if (isA && k < TSTEPS - 1) {
            // P3: AH1(k+1) = A @ H1(k+1) into buf (k+1)&1
            float* AHw = sAH[(k + 1) & 1];
            float aa0[RPT], aa1[RPT];
            #pragma unroll
            for (int r = 0; r < RPT; r++) { aa0[r] = 0.0f; aa1[r] = 0.0f; }
            #pragma unroll 3
            for (int j = 0; j < NN; j++) {
                const float hj0 = sH1[j * HID + f0];
                const float hj1 = sH1[j * HID + f1];
                #pragma unroll
                for (int r = 0; r < RPT; r++) {
                    const float arj = sA[(iA + r) * NN + j];
                    aa0[r] = fmaf(arj, hj0, aa0[r]);
                    aa1[r] = fmaf(arj, hj1, aa1[r]);
                }
            }
            #pragma unroll
            for (int r = 0; r < RPT; r++) {
                AHw[(iA + r) * HID + f0] = aa0[r];
                AHw[(iA + r) * HID + f1] = aa1[r];
            }
        }
        // sax prefetch for step k+2 (threads 0..23, inside group A)
        if (t < NROW && k + 2 < TSTEPS) {
            const float* xt = xb + (size_t)(k + 2) * NN;
            float a = 0.0f;
            for (int j = 0; j < NN; j++) a = fmaf(sA[t * NN + j], xt[j], a);
            sax[(k + 2) & 1][t] = a;
        }
        __syncthreads();   // S2: AH buf + sax published
    }

    // ---------- Epilogue: mean over (T, nodes), dot with cls_w ----------
    if (!isA) {
        sred[gw][f0] = oacc0;
        sred[gw][f1] = oacc1;
    }
    __syncthreads();
    if (t < HID) {
        double s = 0.0;
        for (int gg = 0; gg < 4; gg++) s += sred[gg][t];
        sred[0][t] = (s / (double)(TSTEPS * NN)) * (double)cls_w[t];
    }
    __syncthreads();
    if (t < 64) {
        double v = ((double*)sred)[t] + ((double*)sred)[t + 64];
        for (int off = 32; off; off >>= 1) v += __shfl_down(v, off, 64);
        if (t == 0) out[b] = (float)(v + (double)cls_b[0]);
    }
}

extern "C" void kernel_launch(void* const* d_in, const int* in_sizes, int n_in,
                              void* d_out, int out_size, void* d_ws, size_t ws_size,
                              hipStream_t stream) {
    const float* x    = (const float*)d_in[0];
    const int*   ei   = (const int*)  d_in[1];
    const float* ew   = (const float*)d_in[2];
    const float* Wz1  = (const float*)d_in[3];
    const float* bz1  = (const float*)d_in[4];
    const float* lzw1 = (const float*)d_in[5];
    const float* lzb1 = (const float*)d_in[6];
    const float* Wr1  = (const float*)d_in[7];
    const float* br1  = (const float*)d_in[8];
    const float* lrw1 = (const float*)d_in[9];
    const float* lrb1 = (const float*)d_in[10];
    const float* Wh1  = (const float*)d_in[11];
    const float* bh1  = (const float*)d_in[12];
    const float* lhw1 = (const float*)d_in[13];
    const float* lhb1 = (const float*)d_in[14];
    const float* Wz2  = (const float*)d_in[15];
    const float* bz2  = (const float*)d_in[16];
    const float* lzw2 = (const float*)d_in[17];
    const float* lzb2 = (const float*)d_in[18];
    const float* Wr2  = (const float*)d_in[19];
    const float* br2  = (const float*)d_in[20];
    const float* lrw2 = (const float*)d_in[21];
    const float* lrb2 = (const float*)d_in[22];
    const float* Wh2  = (const float*)d_in[23];
    const float* bh2  = (const float*)d_in[24];
    const float* lhw2 = (const float*)d_in[25];
    const float* lhb2 = (const float*)d_in[26];
    const float* clsw = (const float*)d_in[27];
    const float* clsb = (const float*)d_in[28];

    float* ws   = (float*)d_ws;
    float* outp = (float*)d_out;

    build_A<<<1, 64, 0, stream>>>(ei, ew, ws + WS_A);
    pack_bot<<<32, 256, 0, stream>>>(lzw1, lrw1, (float4*)(ws + WS_LZR1), 2);
    pack_bot<<<16, 256, 0, stream>>>(lhw1, lhw1, (float4*)(ws + WS_LH1), 1);
    pack_bot<<<32, 256, 0, stream>>>(lzw2, lrw2, (float4*)(ws + WS_LZR2), 2);
    pack_bot<<<16, 256, 0, stream>>>(lhw2, lhw2, (float4*)(ws + WS_LH2), 1);
    make_weff2<<<48, 256, 0, stream>>>(Wz2, Wr2, Wh2, lzw2, lrw2, lhw2,
                                       (float4*)(ws + WS_WE2));
    make_vecs<<<5, 256, 0, stream>>>(Wz1, Wr1, Wh1, bz1, br1, bh1,
                                     lzw1, lrw1, lhw1, lzb1, lrb1, lhb1,
                                     bz2, br2, bh2, lzw2, lrw2, lhw2,
                                     lzb2, lrb2, lhb2, ws + WS_VEC);
    tgcn_main<<<64, NTHREADS, 0, stream>>>(x, ws, clsw, clsb, outp);
}

// Round 7
// 12500.006 us; speedup vs baseline: 1.5743x; 1.1988x over previous
//
#include <hip/hip_runtime.h>
#include <hip/hip_bf16.h>

// TGCN: B=64, T=500, N=21, HID=128.
// Round 7: (a) packed-fp32 (v_pk_fma_f32) over the COLUMN pair (f0,f0+64) —
// per-element accumulation chains are bitwise identical to round 6 (only the
// two independent columns share an instruction); weights repacked
// (f,f+64)-interleaved so one b128 = 2k x 2cols. (b) one barrier per tick:
// B-group does P3+P4+P5 for step k (row-local after the tick barrier), A-group
// does P1+P2 for step k+1 into a double-buffered H1. A=waves 0..3 (layer 1),
// B=waves 4..7 (layer 2). NEVER reorder per-element sums in the recurrence.

#define NN 21
#define NROW 24            // padded rows (21,22,23 zero)
#define HID 128
#define TSTEPS 500
#define EDGES 210
#define NTHREADS 512       // 8 waves: 4 per group
#define RPT 6              // rows per thread (within a group)

// ws layout (float offsets)
#define WS_A     0        // NROW*NN floats (pad rows zeroed on build)
#define WS_VEC   1600     // 9*128
#define WS_LZR1  3200     // 32*256*4 floats4 -> 32768 floats
#define WS_LH1   36000    // 32*128*4
#define WS_WE2   52400    // 32*384*4
#define WS_LZR2  101600   // 32*256*4
#define WS_LH2   134400   // 32*128*4

#define WAVE_SYNC() asm volatile("s_waitcnt lgkmcnt(0)" ::: "memory")

typedef float v2f __attribute__((ext_vector_type(2)));

__device__ __forceinline__ v2f lo2(float4 w) { v2f v = {w.x, w.y}; return v; }
__device__ __forceinline__ v2f hi2(float4 w) { v2f v = {w.z, w.w}; return v; }
// acc.{x,y} += s * w.{x,y}  -> v_pk_fma_f32 (s splat via op_sel / mov)
__device__ __forceinline__ void pkf(v2f& acc, float s, v2f w) {
    v2f ss = {s, s};
    acc = __builtin_elementwise_fma(ss, w, acc);
}
__device__ __forceinline__ float sigmoidf(float v) {
    return 1.0f / (1.0f + expf(-v));
}

// ---- Prologue: build normalized adjacency A (21x21) in fp64, store fp32 ----
__global__ void build_A(const int* __restrict__ ei, const float* __restrict__ ew,
                        float* __restrict__ Aout) {
    __shared__ double deg[NN];
    __shared__ double dinv[NN];
    __shared__ double Asm[NN * NN];
    int t = threadIdx.x;
    for (int k = t; k < NN * NN; k += blockDim.x) Asm[k] = 0.0;
    if (t < NN) deg[t] = 1.0;  // self loop weight 1
    __syncthreads();
    if (t == 0) {
        for (int e = 0; e < EDGES; e++) deg[ei[EDGES + e]] += (double)ew[e];
        for (int i = 0; i < NN; i++) dinv[i] = deg[i] > 0.0 ? 1.0 / sqrt(deg[i]) : 0.0;
        for (int e = 0; e < EDGES; e++) {
            int s = ei[e], d = ei[EDGES + e];
            Asm[d * NN + s] += dinv[s] * (double)ew[e] * dinv[d];
        }
        for (int i = 0; i < NN; i++) Asm[i * NN + i] += dinv[i] * dinv[i];
    }
    __syncthreads();
    for (int k = t; k < NROW * NN; k += blockDim.x)
        Aout[k] = (k < NN * NN) ? (float)Asm[k] : 0.0f;
}

// ---- Prologue: repack bottom halves of (256,128) concat weights ----------
// Pair-interleaved layout: float4 idx (c, gate, k2, f0) =
//   c*(ngate*128) + gate*128 + k2*64 + f0,  k = 4c + 2*k2
// contents {w[k][f0], w[k][f0+64], w[k+1][f0], w[k+1][f0+64]}
__global__ void pack_bot(const float* __restrict__ w0, const float* __restrict__ w1,
                         float4* __restrict__ out, int ngate) {
    int t = blockIdx.x * blockDim.x + threadIdx.x;
    int per_c = ngate * 128;
    int total = 32 * per_c;
    if (t >= total) return;
    int c = t / per_c, rem = t - c * per_c;
    int gate = rem >> 7;
    int r2 = rem & 127;
    int k2 = r2 >> 6;
    int f0 = r2 & 63;
    int k = 4 * c + 2 * k2;
    const float* src = (gate == 0) ? w0 : w1;
    float4 v;
    v.x = src[(128 + k) * 128 + f0];
    v.y = src[(128 + k) * 128 + f0 + 64];
    v.z = src[(128 + k + 1) * 128 + f0];
    v.w = src[(128 + k + 1) * 128 + f0 + 64];
    out[t] = v;
}

// ---- Prologue: Weff2_g = Wg_2 @ lgw_2_top, pair-interleaved, fp64 accum ----
__global__ void make_weff2(const float* __restrict__ Wz2, const float* __restrict__ Wr2,
                           const float* __restrict__ Wh2,
                           const float* __restrict__ lzw2, const float* __restrict__ lrw2,
                           const float* __restrict__ lhw2,
                           float4* __restrict__ out) {
    int t = blockIdx.x * blockDim.x + threadIdx.x;  // [0, 32*384)
    if (t >= 32 * 384) return;
    int c = t / 384, rem = t - c * 384;
    int g = rem >> 7;
    int r2 = rem & 127;
    int k2 = r2 >> 6;
    int f0 = r2 & 63;
    int k = 4 * c + 2 * k2;
    const float* W = (g == 0) ? Wz2 : (g == 1) ? Wr2 : Wh2;
    const float* L = (g == 0) ? lzw2 : (g == 1) ? lrw2 : lhw2;
    double a0 = 0, a1 = 0, a2 = 0, a3 = 0;
    for (int m = 0; m < 128; m++) {
        double w0 = (double)W[k * 128 + m];
        double w1 = (double)W[(k + 1) * 128 + m];
        a0 += w0 * (double)L[m * 128 + f0];
        a1 += w0 * (double)L[m * 128 + f0 + 64];
        a2 += w1 * (double)L[m * 128 + f0];
        a3 += w1 * (double)L[m * 128 + f0 + 64];
    }
    out[t] = make_float4((float)a0, (float)a1, (float)a2, (float)a3);
}

// ---- Prologue: layer-1 effective row vectors + all bias consts (fp64) ----
__global__ void make_vecs(const float* __restrict__ Wz1, const float* __restrict__ Wr1,
                          const float* __restrict__ Wh1,
                          const float* __restrict__ bz1, const float* __restrict__ br1,
                          const float* __restrict__ bh1,
                          const float* __restrict__ lzw1, const float* __restrict__ lrw1,
                          const float* __restrict__ lhw1,
                          const float* __restrict__ lzb1, const float* __restrict__ lrb1,
                          const float* __restrict__ lhb1,
                          const float* __restrict__ bz2, const float* __restrict__ br2,
                          const float* __restrict__ bh2,
                          const float* __restrict__ lzw2, const float* __restrict__ lrw2,
                          const float* __restrict__ lhw2,
                          const float* __restrict__ lzb2, const float* __restrict__ lrb2,
                          const float* __restrict__ lhb2,
                          float* __restrict__ out) {
    int t = blockIdx.x * blockDim.x + threadIdx.x;
    if (t >= 9 * 128) return;
    int v = t >> 7, f = t & 127;
    double acc = 0.0;
    if (v < 3) {
        const float* W = (v == 0) ? Wz1 : (v == 1) ? Wr1 : Wh1;   // (1,128)
        const float* L = (v == 0) ? lzw1 : (v == 1) ? lrw1 : lhw1;
        for (int m = 0; m < 128; m++) acc += (double)W[m] * (double)L[m * 128 + f];
    } else if (v < 6) {
        int g = v - 3;
        const float* bb = (g == 0) ? bz1 : (g == 1) ? br1 : bh1;
        const float* L  = (g == 0) ? lzw1 : (g == 1) ? lrw1 : lhw1;
        const float* lb = (g == 0) ? lzb1 : (g == 1) ? lrb1 : lhb1;
        for (int m = 0; m < 128; m++) acc += (double)bb[m] * (double)L[m * 128 + f];
        acc += (double)lb[f];
    } else {
        int g = v - 6;
        const float* bb = (g == 0) ? bz2 : (g == 1) ? br2 : bh2;
        const float* L  = (g == 0) ? lzw2 : (g == 1) ? lrw2 : lhw2;
        const float* lb = (g == 0) ? lzb2 : (g == 1) ? lrb2 : lhb2;
        for (int m = 0; m < 128; m++) acc += (double)bb[m] * (double)L[m * 128 + f];
        acc += (double)lb[f];
    }
    out[t] = (float)acc;
}

// ---- Main: one block per batch, layer-pipelined groups, 1 barrier/tick ----
__global__ __launch_bounds__(NTHREADS, 2) void tgcn_main(
    const float* __restrict__ x,       // (64,500,21)
    const float* __restrict__ ws,
    const float* __restrict__ cls_w,   // (128,1)
    const float* __restrict__ cls_b,   // (1,)
    float* __restrict__ out)           // (64,)
{
    const int b  = blockIdx.x;
    const int t  = threadIdx.x;
    const bool isA = (t < 256);                              // wave-uniform
    const int lt = t & 255;
    const int f0 = lt & 63;
    const int f1 = f0 + 64;
    const int gw = __builtin_amdgcn_readfirstlane(lt >> 6);  // 0..3 in group
    const int iA = gw * RPT;
    const int nreal = (iA + RPT <= NN) ? RPT : (NN - iA);

    __shared__ __align__(16) float sH1[2][NROW * HID];  // double-buffered
    __shared__ __align__(16) float sH2[NROW * HID];
    __shared__ __align__(16) float sHR1[NROW * HID];
    __shared__ __align__(16) float sHR2[NROW * HID];
    __shared__ __align__(16) float sAH[NROW * HID];     // B-private, per tick
    __shared__ float sA[NROW * NN];
    __shared__ float sax[2][NROW];
    __shared__ double sred[4][HID];

    const float*  vecs = ws + WS_VEC;
    const float4* Lzr1 = (const float4*)(ws + WS_LZR1);
    const float4* Lh1  = (const float4*)(ws + WS_LH1);
    const float4* We2  = (const float4*)(ws + WS_WE2);
    const float4* Lzr2 = (const float4*)(ws + WS_LZR2);
    const float4* Lh2  = (const float4*)(ws + WS_LH2);

    const float4* H2v  = (const float4*)sH2;
    const float4* HR1v = (const float4*)sHR1;
    const float4* HR2v = (const float4*)sHR2;
    const float4* AHv  = (const float4*)sAH;

    for (int k = t; k < 2 * NROW * HID; k += NTHREADS) ((float*)sH1)[k] = 0.0f;
    for (int k = t; k < NROW * HID; k += NTHREADS) sH2[k] = 0.0f;
    for (int k = t; k < NROW * NN; k += NTHREADS) sA[k] = ws[WS_A + k];

    // per-column-pair constants
    const v2f wz1v = {vecs[f0],        vecs[f1]};
    const v2f wr1v = {vecs[128 + f0],  vecs[128 + f1]};
    const v2f wh1v = {vecs[256 + f0],  vecs[256 + f1]};
    const v2f cz1v = {vecs[384 + f0],  vecs[384 + f1]};
    const v2f cr1v = {vecs[512 + f0],  vecs[512 + f1]};
    const v2f ch1v = {vecs[640 + f0],  vecs[640 + f1]};
    const v2f cz2v = {vecs[768 + f0],  vecs[768 + f1]};
    const v2f cr2v = {vecs[896 + f0],  vecs[896 + f1]};
    const v2f ch2v = {vecs[1024 + f0], vecs[1024 + f1]};

    __syncthreads();

    const float* xb = x + (size_t)b * (TSTEPS * NN);
    if (t < NROW) {  // sax for steps 0 and 1 (slot = s&1)
        float a0s = 0.0f, a1s = 0.0f;
        for (int j = 0; j < NN; j++) {
            a0s = fmaf(sA[t * NN + j], xb[j], a0s);
            a1s = fmaf(sA[t * NN + j], xb[NN + j], a1s);
        }
        sax[0][t] = a0s;
        sax[1][t] = a1s;
    }
    __syncthreads();

    double oacc0 = 0.0, oacc1 = 0.0;   // group B only

    // ============ A-group layer-1 body (step s: read buf (s+1)&1, write s&1) ==
    // Implemented inline twice (prologue s=0, loop s=k+1) via a lambda.
    auto layer1 = [&](int s) {
        const float* H1rd = sH1[(s + 1) & 1];   // state after step s-1
        float*       H1wr = sH1[s & 1];
        const float4* H1c = (const float4*)H1rd;
        float axp[RPT];
        #pragma unroll
        for (int r = 0; r < RPT; r++) axp[r] = sax[s & 1][iA + r];
        // P1: z,r gates
        v2f az[RPT], ar[RPT];
        #pragma unroll
        for (int r = 0; r < RPT; r++) {
            az[r] = __builtin_elementwise_fma((v2f){axp[r], axp[r]}, wz1v, cz1v);
            ar[r] = __builtin_elementwise_fma((v2f){axp[r], axp[r]}, wr1v, cr1v);
        }
        #pragma unroll 2
        for (int c = 0; c < 32; ++c) {
            const float4 wz0 = Lzr1[c * 256 + f0];
            const float4 wz1 = Lzr1[c * 256 + 64 + f0];
            const float4 wr0 = Lzr1[c * 256 + 128 + f0];
            const float4 wr1 = Lzr1[c * 256 + 192 + f0];
            #pragma unroll
            for (int r = 0; r < RPT; r++) {
                const float4 h = H1c[(iA + r) * 32 + c];
                pkf(az[r], h.x, lo2(wz0)); pkf(az[r], h.y, hi2(wz0));
                pkf(az[r], h.z, lo2(wz1)); pkf(az[r], h.w, hi2(wz1));
                pkf(ar[r], h.x, lo2(wr0)); pkf(ar[r], h.y, hi2(wr0));
                pkf(ar[r], h.z, lo2(wr1)); pkf(ar[r], h.w, hi2(wr1));
            }
        }
        v2f zg[RPT], h1c[RPT];
        #pragma unroll
        for (int r = 0; r < RPT; r++) {
            zg[r].x = sigmoidf(az[r].x);
            zg[r].y = sigmoidf(az[r].y);
            const float r0 = sigmoidf(ar[r].x);
            const float r1 = sigmoidf(ar[r].y);
            h1c[r].x = H1rd[(iA + r) * HID + f0];
            h1c[r].y = H1rd[(iA + r) * HID + f1];
            sHR1[(iA + r) * HID + f0] = h1c[r].x * r0;
            sHR1[(iA + r) * HID + f1] = h1c[r].y * r1;
        }
        WAVE_SYNC();
        // P2: h gate + H1 update
        v2f ah[RPT];
        #pragma unroll
        for (int r = 0; r < RPT; r++)
            ah[r] = __builtin_elementwise_fma((v2f){axp[r], axp[r]}, wh1v, ch1v);
        #pragma unroll 2
        for (int c = 0; c < 32; ++c) {
            const float4 wh0 = Lh1[c * 128 + f0];
            const float4 wh1 = Lh1[c * 128 + 64 + f0];
            #pragma unroll
            for (int r = 0; r < RPT; r++) {
                const float4 q = HR1v[(iA + r) * 32 + c];
                pkf(ah[r], q.x, lo2(wh0)); pkf(ah[r], q.y, hi2(wh0));
                pkf(ah[r], q.z, lo2(wh1)); pkf(ah[r], q.w, hi2(wh1));
            }
        }
        #pragma unroll
        for (int r = 0; r < RPT; r++) {
            const float n0 = fmaf(zg[r].x, h1c[r].x, (1.0f - zg[r].x) * tanhf(ah[r].x));
            const float n1 = fmaf(zg[r].y, h1c[r].y, (1.0f - zg[r].y) * tanhf(ah[r].y));
            H1wr[(iA + r) * HID + f0] = n0;
            H1wr[(iA + r) * HID + f1] = n1;
        }
    };

    // ======== pipeline prologue: A computes step 0 (reads zeroed buf 1) ======
    if (isA) layer1(0);
    __syncthreads();

    // ======== main ticks: A does step k+1, B does step k (ONE barrier) ======
    for (int k = 0; k < TSTEPS; k++) {
        if (isA) {
            if (k + 1 < TSTEPS) {
                layer1(k + 1);
                // sax prefetch for step k+2 (threads 0..23 = wave 0 = A)
                if (t < NROW && k + 2 < TSTEPS) {
                    const float* xt = xb + (size_t)(k + 2) * NN;
                    float a = 0.0f;
                    for (int j = 0; j < NN; j++) a = fmaf(sA[t * NN + j], xt[j], a);
                    sax[(k + 2) & 1][t] = a;
                }
            }
        } else {
            // ----- group B: step k -----
            const float* H1rd = sH1[k & 1];   // state after step k
            // P3: AH = A @ H1 (own rows; reads all H1 rows, published at barrier)
            v2f aa[RPT];
            #pragma unroll
            for (int r = 0; r < RPT; r++) aa[r] = (v2f){0.0f, 0.0f};
            #pragma unroll 3
            for (int j = 0; j < NN; j++) {
                const v2f hj = {H1rd[j * HID + f0], H1rd[j * HID + f1]};
                #pragma unroll
                for (int r = 0; r < RPT; r++) {
                    const float arj = sA[(iA + r) * NN + j];
                    acc_p3: ;
                    aa[r] = __builtin_elementwise_fma((v2f){arj, arj}, hj, aa[r]);
                }
            }
            #pragma unroll
            for (int r = 0; r < RPT; r++) {
                sAH[(iA + r) * HID + f0] = aa[r].x;
                sAH[(iA + r) * HID + f1] = aa[r].y;
            }
            WAVE_SYNC();
            // P4: layer-2 gcn + z,r gates
            v2f pz[RPT], pr[RPT], ph[RPT];
            #pragma unroll
            for (int r = 0; r < RPT; r++) { pz[r] = cz2v; pr[r] = cr2v; ph[r] = ch2v; }
            for (int c = 0; c < 32; ++c) {
                const float4 wz0 = We2[c * 384 + f0];
                const float4 wz1 = We2[c * 384 + 64 + f0];
                const float4 wr0 = We2[c * 384 + 128 + f0];
                const float4 wr1 = We2[c * 384 + 192 + f0];
                const float4 wh0 = We2[c * 384 + 256 + f0];
                const float4 wh1 = We2[c * 384 + 320 + f0];
                const float4 lz0 = Lzr2[c * 256 + f0];
                const float4 lz1 = Lzr2[c * 256 + 64 + f0];
                const float4 lr0 = Lzr2[c * 256 + 128 + f0];
                const float4 lr1 = Lzr2[c * 256 + 192 + f0];
                #pragma unroll
                for (int r = 0; r < RPT; r++) {
                    const float4 a = AHv[(iA + r) * 32 + c];
                    const float4 q = H2v[(iA + r) * 32 + c];
                    // a-chunk then q-chunk per c (round-4/6 order)
                    pkf(pz[r], a.x, lo2(wz0)); pkf(pz[r], a.y, hi2(wz0));
                    pkf(pz[r], a.z, lo2(wz1)); pkf(pz[r], a.w, hi2(wz1));
                    pkf(pz[r], q.x, lo2(lz0)); pkf(pz[r], q.y, hi2(lz0));
                    pkf(pz[r], q.z, lo2(lz1)); pkf(pz[r], q.w, hi2(lz1));
                    pkf(pr[r], a.x, lo2(wr0)); pkf(pr[r], a.y, hi2(wr0));
                    pkf(pr[r], a.z, lo2(wr1)); pkf(pr[r], a.w, hi2(wr1));
                    pkf(pr[r], q.x, lo2(lr0)); pkf(pr[r], q.y, hi2(lr0));
                    pkf(pr[r], q.z, lo2(lr1)); pkf(pr[r], q.w, hi2(lr1));
                    pkf(ph[r], a.x, lo2(wh0)); pkf(ph[r], a.y, hi2(wh0));
                    pkf(ph[r], a.z, lo2(wh1)); pkf(ph[r], a.w, hi2(wh1));
                }
            }
            v2f z2[RPT], h2c[RPT];
            #pragma unroll
            for (int r = 0; r < RPT; r++) {
                z2[r].x = sigmoidf(pz[r].x);
                z2[r].y = sigmoidf(pz[r].y);
                const float r20 = sigmoidf(pr[r].x);
                const float r21 = sigmoidf(pr[r].y);
                h2c[r].x = sH2[(iA + r) * HID + f0];
                h2c[r].y = sH2[(iA + r) * HID + f1];
                sHR2[(iA + r) * HID + f0] = h2c[r].x * r20;
                sHR2[(iA + r) * HID + f1] = h2c[r].y * r21;
            }
            WAVE_SYNC();
            // P5: layer-2 h gate + H2 update + output accum
            #pragma unroll 2
            for (int c = 0; c < 32; ++c) {
                const float4 lh0 = Lh2[c * 128 + f0];
                const float4 lh1 = Lh2[c * 128 + 64 + f0];
                #pragma unroll
                for (int r = 0; r < RPT; r++) {
                    const float4 q = HR2v[(iA + r) * 32 + c];
                    pkf(ph[r], q.x, lo2(lh0)); pkf(ph[r], q.y, hi2(lh0));
                    pkf(ph[r], q.z, lo2(lh1)); pkf(ph[r], q.w, hi2(lh1));
                }
            }
            #pragma unroll
            for (int r = 0; r < RPT; r++) {
                const float m0 = fmaf(z2[r].x, h2c[r].x, (1.0f - z2[r].x) * tanhf(ph[r].x));
                const float m1 = fmaf(z2[r].y, h2c[r].y, (1.0f - z2[r].y) * tanhf(ph[r].y));
                sH2[(iA + r) * HID + f0] = m0;
                sH2[(iA + r) * HID + f1] = m1;
                if (r < nreal) {
                    oacc0 += (double)m0;
                    oacc1 += (double)m1;
                }
            }
        }
        __syncthreads();   // the ONE tick barrier: publishes H1(k+1), sax(k+2)
    }

    // ---------- Epilogue: mean over (T, nodes), dot with cls_w ----------
    if (!isA) {
        sred[gw][f0] = oacc0;
        sred[gw][f1] = oacc1;
    }
    __syncthreads();
    if (t < HID) {
        double s = 0.0;
        for (int gg = 0; gg < 4; gg++) s += sred[gg][t];
        sred[0][t] = (s / (double)(TSTEPS * NN)) * (double)cls_w[t];
    }
    __syncthreads();
    if (t < 64) {
        double v = ((double*)sred)[t] + ((double*)sred)[t + 64];
        for (int off = 32; off; off >>= 1) v += __shfl_down(v, off, 64);
        if (t == 0) out[b] = (float)(v + (double)cls_b[0]);
    }
}

extern "C" void kernel_launch(void* const* d_in, const int* in_sizes, int n_in,
                              void* d_out, int out_size, void* d_ws, size_t ws_size,
                              hipStream_t stream) {
    const float* x    = (const float*)d_in[0];
    const int*   ei   = (const int*)  d_in[1];
    const float* ew   = (const float*)d_in[2];
    const float* Wz1  = (const float*)d_in[3];
    const float* bz1  = (const float*)d_in[4];
    const float* lzw1 = (const float*)d_in[5];
    const float* lzb1 = (const float*)d_in[6];
    const float* Wr1  = (const float*)d_in[7];
    const float* br1  = (const float*)d_in[8];
    const float* lrw1 = (const float*)d_in[9];
    const float* lrb1 = (const float*)d_in[10];
    const float* Wh1  = (const float*)d_in[11];
    const float* bh1  = (const float*)d_in[12];
    const float* lhw1 = (const float*)d_in[13];
    const float* lhb1 = (const float*)d_in[14];
    const float* Wz2  = (const float*)d_in[15];
    const float* bz2  = (const float*)d_in[16];
    const float* lzw2 = (const float*)d_in[17];
    const float* lzb2 = (const float*)d_in[18];
    const float* Wr2  = (const float*)d_in[19];
    const float* br2  = (const float*)d_in[20];
    const float* lrw2 = (const float*)d_in[21];
    const float* lrb2 = (const float*)d_in[22];
    const float* Wh2  = (const float*)d_in[23];
    const float* bh2  = (const float*)d_in[24];
    const float* lhw2 = (const float*)d_in[25];
    const float* lhb2 = (const float*)d_in[26];
    const float* clsw = (const float*)d_in[27];
    const float* clsb = (const float*)d_in[28];

    float* ws   = (float*)d_ws;
    float* outp = (float*)d_out;

    build_A<<<1, 64, 0, stream>>>(ei, ew, ws + WS_A);
    pack_bot<<<32, 256, 0, stream>>>(lzw1, lrw1, (float4*)(ws + WS_LZR1), 2);
    pack_bot<<<16, 256, 0, stream>>>(lhw1, lhw1, (float4*)(ws + WS_LH1), 1);
    pack_bot<<<32, 256, 0, stream>>>(lzw2, lrw2, (float4*)(ws + WS_LZR2), 2);
    pack_bot<<<16, 256, 0, stream>>>(lhw2, lhw2, (float4*)(ws + WS_LH2), 1);
    make_weff2<<<48, 256, 0, stream>>>(Wz2, Wr2, Wh2, lzw2, lrw2, lhw2,
                                       (float4*)(ws + WS_WE2));
    make_vecs<<<5, 256, 0, stream>>>(Wz1, Wr1, Wh1, bz1, br1, bh1,
                                     lzw1, lrw1, lhw1, lzb1, lrb1, lhb1,
                                     bz2, br2, bh2, lzw2, lrw2, lhw2,
                                     lzb2, lrb2, lhb2, ws + WS_VEC);
    tgcn_main<<<64, NTHREADS, 0, stream>>>(x, ws, clsw, clsb, outp);
}